// Round 3
// baseline (410.389 us; speedup 1.0000x reference)
//
#include <hip/hip_runtime.h>

#define B_    32
#define NW_   64
#define BW_   2048   // B*NW
#define L_    49
#define D_    192
#define PROJ_ 256
#define H_    8
#define HD_   32

typedef __attribute__((ext_vector_type(8))) short bf16x8;
typedef __attribute__((ext_vector_type(4))) float f32x4;

// ---------------------------------------------------------------------------
// Dynamic LDS layout (76800 B -> 2 blocks/CU, 512 thr -> 16 waves/CU = 4/SIMD):
//   [0,     24576)  Xb: staged input bf16, row l at l*384 (384B = full row,
//                   no pad), byte ^= (l&7)<<4.  After the post-sel2 barrier,
//                   overlaid by per-WAVE V^T half-slots: slot w at w*2560,
//                   [c:32][kk-half:32] bf16, row pitch 80 B (pitch-5*16 ->
//                   2-way max in 16-lane phases). Halves staged sequentially.
//   [24576, 74752)  per-head 6272 B (8 heads, head == wave):
//                     proj:  q rows [49][32] at +0 (row i 64B,
//                            byte ^= ((i>>1)&3)<<4), k at +3136 (same swz)
//                     attn:  P rows [49][64] overlays q+k; row q 128 B,
//                            byte ^= (q&7)<<4
//                     out:   O rows [49][32] overlays q; same swz as q/k
//   [74752, 75264)  mrow: 64 x u64 mask row-bitmasks (built in-block)
//   [75264, 76800)  pad: keeps deliberate pad-row (row 49..63) reads, which
//                   bleed past head 7's slot, inside the allocation
// All pad-row reads feed lanes whose outputs are masked (-inf) or dropped
// (i<L_ guards); writes are always guarded to rows < 49 / in-slot.
// ---------------------------------------------------------------------------
#define QK_OFF    24576
#define MROW_OFF  74752
#define LDS_BYTES 76800

__device__ __forceinline__ short f2bf(float f) {
    union { float f; unsigned u; } v; v.f = f;
    unsigned r = v.u + 0x7FFFu + ((v.u >> 16) & 1u);   // RNE
    return (short)(r >> 16);
}

// packed f32x2 -> bf16x2 (RNE, bit-identical to f2bf for finite values)
__device__ __forceinline__ unsigned cvtpk(float lo, float hi) {
    unsigned r;
    asm("v_cvt_pk_bf16_f32 %0, %1, %2" : "=v"(r) : "v"(lo), "v"(hi));
    return r;
}

// ---------------------------------------------------------------------------
// Weight prep only (mask folded into fused kernel). grid 960 x 256:
//   b<768 : Wq/Wk/Wv (192x256 -> Wt[n][k], k contiguous)
//   else  : Ww (256x192 -> Wwt[n][k])
// ---------------------------------------------------------------------------
__global__ __launch_bounds__(256) void prep_weights(
    const float* __restrict__ Wq, const float* __restrict__ Wk,
    const float* __restrict__ Wv, const float* __restrict__ Ww,
    short* __restrict__ Wqt, short* __restrict__ Wkt,
    short* __restrict__ Wvt, short* __restrict__ Wwt)
{
    const int b   = blockIdx.x;
    const int tid = threadIdx.x;
    if (b < 768) {
        const int sel = b >> 8, n = b & 255;
        const float* src = (sel == 0) ? Wq : (sel == 1) ? Wk : Wv;
        short* dst = (sel == 0) ? Wqt : (sel == 1) ? Wkt : Wvt;
        if (tid < D_) dst[n * D_ + tid] = f2bf(src[tid * PROJ_ + n]);
    } else {
        const int n = b - 768;                    // 0..191
        Wwt[n * PROJ_ + tid] = f2bf(Ww[tid * D_ + n]);
    }
}

// ---------------------------------------------------------------------------
// Fully fused window attention. One block per window, 512 threads = 8 waves,
// wave w == head w. q/k via LDS transpose; P via per-head LDS; V^T via
// per-wave half-slots; everything wave-private between the staging barriers
// and the single out-proj barrier.
// ---------------------------------------------------------------------------
__global__ __launch_bounds__(512, 4) void fused_kernel(
    const float* __restrict__ query, const float* __restrict__ key_,
    const float* __restrict__ value,
    const short* __restrict__ Wqt, const short* __restrict__ Wkt,
    const short* __restrict__ Wvt,
    const float* __restrict__ bq, const float* __restrict__ bk,
    const int* __restrict__ mask,
    const short* __restrict__ Wwt, const float* __restrict__ bwb,
    float* __restrict__ out)
{
    extern __shared__ char lds[];

    const int bw   = blockIdx.x;
    const int w    = bw & (NW_ - 1);
    const int tid  = threadIdx.x;
    const int wave = tid >> 6;          // == head
    const int lane = tid & 63;
    const int m16  = lane & 15;
    const int quad = lane >> 4;

    const int swz2 = ((m16 >> 1) & 3) << 4;   // [49][32] regions (q/k/O)
    const int swz3 = (m16 & 7) << 4;          // [..][64]/[..][192] (Xb/P)

    char* qb = lds + QK_OFF + wave * 6272;    // head's q (later O)
    char* kb = qb + 3136;                     // head's k
    char* vslot = lds + wave * 2560;          // V^T half-slot (overlays Xb)
    unsigned long long* mrow = (unsigned long long*)(lds + MROW_OFF);

    uint2 vpk[2][4];   // packed V fragments, staged out in halves

    // ---------------- QKV projection (1 head per wave) ----------------
    #pragma unroll
    for (int sel = 0; sel < 3; ++sel) {
        const float* x  = (sel == 0) ? query : (sel == 1) ? key_ : value;
        const short* Wt = (sel == 0) ? Wqt : (sel == 1) ? Wkt : Wvt;

        __syncthreads();   // previous users of Xb done
        #pragma unroll
        for (int it = 0; it < 6; ++it) {
            const int i = tid + it * 512;            // 0..3071
            const int l = i / 48, c4 = i - l * 48;
            uint2 u = {0u, 0u};
            if (l < L_) {
                float4 v = *(const float4*)&x[((size_t)bw * L_ + l) * D_ + c4 * 4];
                u.x = cvtpk(v.x, v.y); u.y = cvtpk(v.z, v.w);
            }
            *(uint2*)(lds + l * 384 + ((c4 * 8) ^ ((l & 7) << 4))) = u;
        }
        if (sel == 0) {
            // mask row bitmasks: wave handles rows wave*8 .. +7
            #pragma unroll
            for (int rr = 0; rr < 8; ++rr) {
                const int row = wave * 8 + rr;
                int val = 0;
                if (row < L_ && lane < L_)
                    val = mask[w * (L_ * L_) + row * L_ + lane];
                unsigned long long bits = __ballot(val != 0);
                if (lane == 0) mrow[row] = bits;
            }
        }
        __syncthreads();

        f32x4 acc[4][2];
        #pragma unroll
        for (int mt = 0; mt < 4; ++mt)
            #pragma unroll
            for (int nt = 0; nt < 2; ++nt)
                acc[mt][nt] = (f32x4){0.f, 0.f, 0.f, 0.f};

        #pragma unroll
        for (int kc = 0; kc < 6; ++kc) {
            bf16x8 af[4], bfr[2];
            #pragma unroll
            for (int mt = 0; mt < 4; ++mt)
                af[mt] = *(const bf16x8*)(lds + (mt * 16 + m16) * 384 +
                                          ((kc * 64 + quad * 16) ^ swz3));
            #pragma unroll
            for (int nt = 0; nt < 2; ++nt)
                bfr[nt] = *(const bf16x8*)&Wt[(size_t)(wave * 32 + nt * 16 + m16) * D_ +
                                              kc * 32 + quad * 8];
            __builtin_amdgcn_s_setprio(1);
            #pragma unroll
            for (int mt = 0; mt < 4; ++mt)
                #pragma unroll
                for (int nt = 0; nt < 2; ++nt)
                    acc[mt][nt] = __builtin_amdgcn_mfma_f32_16x16x32_bf16(
                        af[mt], bfr[nt], acc[mt][nt], 0, 0, 0);
            __builtin_amdgcn_s_setprio(0);
        }

        if (sel < 2) {
            // q/k: [49][32], swizzled 2-byte scatter (wave-private region)
            const float* bsel = (sel == 0) ? bq : bk;
            char* db = (sel == 0) ? qb : kb;
            #pragma unroll
            for (int nt = 0; nt < 2; ++nt) {
                const int c = nt * 16 + m16;
                const float bias = bsel[wave * 32 + c];
                #pragma unroll
                for (int mt = 0; mt < 4; ++mt)
                    #pragma unroll
                    for (int r = 0; r < 4; ++r) {
                        const int i = mt * 16 + quad * 4 + r;
                        if (i < L_)
                            *(short*)(db + i * 64 + ((2 * c) ^ (((i >> 1) & 3) << 4))) =
                                f2bf(acc[mt][nt][r] + bias);
                    }
            }
        } else {
            // V kept packed in registers; staged to LDS in halves later
            #pragma unroll
            for (int nt = 0; nt < 2; ++nt)
                #pragma unroll
                for (int mt = 0; mt < 4; ++mt) {
                    vpk[nt][mt].x = cvtpk(acc[mt][nt][0], acc[mt][nt][1]);
                    vpk[nt][mt].y = cvtpk(acc[mt][nt][2], acc[mt][nt][3]);
                }
        }
    }

    __syncthreads();   // all Xb fragment reads done -> V slots may overlay

    // stage V^T half0 (kk 0..31 = mt 0,1): row c, pitch 80
    #pragma unroll
    for (int nt = 0; nt < 2; ++nt)
        #pragma unroll
        for (int mt = 0; mt < 2; ++mt)
            *(uint2*)(vslot + (nt * 16 + m16) * 80 + mt * 32 + quad * 8) = vpk[nt][mt];

    // mask bitmasks for this lane's 4 q-rows
    unsigned long long mb[4];
    #pragma unroll
    for (int nt = 0; nt < 4; ++nt) mb[nt] = mrow[nt * 16 + m16];

    const float scale = 0.17677669529663687f;  // 1/sqrt(32)

    // ---- S^T = K @ Q^T : lane holds S[q=16nt+m16][k=16mt+4quad+r] ----
    f32x4 sacc[4][4];
    #pragma unroll
    for (int mt = 0; mt < 4; ++mt)
        #pragma unroll
        for (int nt = 0; nt < 4; ++nt)
            sacc[mt][nt] = (f32x4){0.f, 0.f, 0.f, 0.f};
    {
        bf16x8 kf[4], qf[4];
        #pragma unroll
        for (int mt = 0; mt < 4; ++mt)
            kf[mt] = *(const bf16x8*)(kb + (mt * 16 + m16) * 64 + ((quad * 16) ^ swz2));
        #pragma unroll
        for (int nt = 0; nt < 4; ++nt)
            qf[nt] = *(const bf16x8*)(qb + (nt * 16 + m16) * 64 + ((quad * 16) ^ swz2));
        __builtin_amdgcn_s_setprio(1);
        #pragma unroll
        for (int mt = 0; mt < 4; ++mt)
            #pragma unroll
            for (int nt = 0; nt < 4; ++nt)
                sacc[mt][nt] = __builtin_amdgcn_mfma_f32_16x16x32_bf16(
                    kf[mt], qf[nt], sacc[mt][nt], 0, 0, 0);
        __builtin_amdgcn_s_setprio(0);
    }

    // ---- softmax per q-row (in-lane over 16 k + 2 quad shuffles); P -> LDS ----
    #pragma unroll
    for (int nt = 0; nt < 4; ++nt) {
        float e[4][4];
        float mx = -1e30f;
        #pragma unroll
        for (int mt = 0; mt < 4; ++mt)
            #pragma unroll
            for (int r = 0; r < 4; ++r) {
                const int k = mt * 16 + quad * 4 + r;
                float v = sacc[mt][nt][r] * scale;
                if (k >= L_) v = -INFINITY;                  // pad cols: exact 0
                else if ((mb[nt] >> k) & 1ull) v = -1000.0f; // ref semantics
                e[mt][r] = v;
                mx = fmaxf(mx, v);
            }
        mx = fmaxf(mx, __shfl_xor(mx, 16, 64));
        mx = fmaxf(mx, __shfl_xor(mx, 32, 64));
        float sum = 0.f;
        #pragma unroll
        for (int mt = 0; mt < 4; ++mt)
            #pragma unroll
            for (int r = 0; r < 4; ++r) {
                const float ev = __expf(e[mt][r] - mx);
                e[mt][r] = ev;
                sum += ev;
            }
        sum += __shfl_xor(sum, 16, 64);
        sum += __shfl_xor(sum, 32, 64);
        const float inv = 1.0f / sum;
        const int prow = nt * 16 + m16;
        if (prow < L_) {
            #pragma unroll
            for (int mt = 0; mt < 4; ++mt) {
                uint2 p;
                p.x = cvtpk(e[mt][0] * inv, e[mt][1] * inv);
                p.y = cvtpk(e[mt][2] * inv, e[mt][3] * inv);
                *(uint2*)(qb + prow * 128 + ((mt * 32 + quad * 8) ^ swz3)) = p;
            }
        }
    }

    // ---- O^T = V^T @ P^T, K=64 in 2 halves (V slot restaged between) ----
    f32x4 oacc[2][4];
    #pragma unroll
    for (int mt2 = 0; mt2 < 2; ++mt2)
        #pragma unroll
        for (int nt = 0; nt < 4; ++nt)
            oacc[mt2][nt] = (f32x4){0.f, 0.f, 0.f, 0.f};
    #pragma unroll
    for (int kc = 0; kc < 2; ++kc) {
        bf16x8 vf[2], pf[4];
        #pragma unroll
        for (int mt2 = 0; mt2 < 2; ++mt2)
            vf[mt2] = *(const bf16x8*)(vslot + (mt2 * 16 + m16) * 80 + quad * 16);
        #pragma unroll
        for (int nt = 0; nt < 4; ++nt)
            pf[nt] = *(const bf16x8*)(qb + (nt * 16 + m16) * 128 +
                                      ((kc * 64 + quad * 16) ^ swz3));
        __builtin_amdgcn_s_setprio(1);
        #pragma unroll
        for (int mt2 = 0; mt2 < 2; ++mt2)
            #pragma unroll
            for (int nt = 0; nt < 4; ++nt)
                oacc[mt2][nt] = __builtin_amdgcn_mfma_f32_16x16x32_bf16(
                    vf[mt2], pf[nt], oacc[mt2][nt], 0, 0, 0);
        __builtin_amdgcn_s_setprio(0);
        if (kc == 0) {
            // stage half1 (kk 32..63 = mt 2,3); same in-slot addresses.
            // DS ops are in-order per wave, so kc1's reads see these writes.
            #pragma unroll
            for (int nt = 0; nt < 2; ++nt)
                #pragma unroll
                for (int mt = 2; mt < 4; ++mt)
                    *(uint2*)(vslot + (nt * 16 + m16) * 80 + (mt - 2) * 32 + quad * 8) =
                        vpk[nt][mt];
        }
    }

    // O ([49][32], A-layout-ready) overlays q
    #pragma unroll
    for (int nt = 0; nt < 4; ++nt) {
        const int prow = nt * 16 + m16;
        if (prow < L_) {
            #pragma unroll
            for (int mt2 = 0; mt2 < 2; ++mt2) {
                uint2 o;
                o.x = cvtpk(oacc[mt2][nt][0], oacc[mt2][nt][1]);
                o.y = cvtpk(oacc[mt2][nt][2], oacc[mt2][nt][3]);
                *(uint2*)(qb + prow * 64 +
                          ((mt2 * 32 + quad * 8) ^ (((prow >> 1) & 3) << 4))) = o;
            }
        }
    }

    __syncthreads();   // all heads' O ready

    // ---- out-proj: out = O @ Ww + bw, K=256. 12 col-tiles over 8 waves ----
    f32x4 cacc[4][2];
    #pragma unroll
    for (int mt = 0; mt < 4; ++mt)
        #pragma unroll
        for (int nt = 0; nt < 2; ++nt)
            cacc[mt][nt] = (f32x4){0.f, 0.f, 0.f, 0.f};
    #pragma unroll
    for (int kc = 0; kc < 8; ++kc) {
        char* Oh = lds + QK_OFF + kc * 6272;    // head kc's O
        bf16x8 af[4], bfw[2];
        #pragma unroll
        for (int mt = 0; mt < 4; ++mt)
            af[mt] = *(const bf16x8*)(Oh + (mt * 16 + m16) * 64 + ((quad * 16) ^ swz2));
        bfw[0] = *(const bf16x8*)&Wwt[(size_t)(wave * 16 + m16) * PROJ_ +
                                      kc * 32 + quad * 8];
        if (wave < 4)
            bfw[1] = *(const bf16x8*)&Wwt[(size_t)(128 + wave * 16 + m16) * PROJ_ +
                                          kc * 32 + quad * 8];
        __builtin_amdgcn_s_setprio(1);
        #pragma unroll
        for (int mt = 0; mt < 4; ++mt) {
            cacc[mt][0] = __builtin_amdgcn_mfma_f32_16x16x32_bf16(
                af[mt], bfw[0], cacc[mt][0], 0, 0, 0);
            if (wave < 4)
                cacc[mt][1] = __builtin_amdgcn_mfma_f32_16x16x32_bf16(
                    af[mt], bfw[1], cacc[mt][1], 0, 0, 0);
        }
        __builtin_amdgcn_s_setprio(0);
    }
    #pragma unroll
    for (int nt = 0; nt < 2; ++nt) {
        if (nt == 0 || wave < 4) {
            const int col = nt * 128 + wave * 16 + m16;
            const float bias = bwb[col];
            #pragma unroll
            for (int mt = 0; mt < 4; ++mt)
                #pragma unroll
                for (int r = 0; r < 4; ++r) {
                    const int i = mt * 16 + quad * 4 + r;
                    if (i < L_)
                        out[((size_t)bw * L_ + i) * D_ + col] = cacc[mt][nt][r] + bias;
                }
        }
    }
}

extern "C" void kernel_launch(void* const* d_in, const int* in_sizes, int n_in,
                              void* d_out, int out_size, void* d_ws, size_t ws_size,
                              hipStream_t stream) {
    const float* query = (const float*)d_in[0];
    const float* key_  = (const float*)d_in[1];
    const float* value = (const float*)d_in[2];
    const int*   mask  = (const int*)d_in[3];
    const float* Wq    = (const float*)d_in[4];
    const float* bq    = (const float*)d_in[5];
    const float* Wk    = (const float*)d_in[6];
    const float* bk    = (const float*)d_in[7];
    const float* Wv    = (const float*)d_in[8];
    const float* Ww    = (const float*)d_in[9];
    const float* bw    = (const float*)d_in[10];
    float* out = (float*)d_out;

    short* Wqt = (short*)d_ws;
    short* Wkt = Wqt + PROJ_ * D_;
    short* Wvt = Wkt + PROJ_ * D_;
    short* Wwt = Wvt + PROJ_ * D_;

    static bool attr_set = false;
    if (!attr_set) {
        (void)hipFuncSetAttribute(reinterpret_cast<const void*>(fused_kernel),
                                  hipFuncAttributeMaxDynamicSharedMemorySize, LDS_BYTES);
        attr_set = true;
    }

    prep_weights<<<dim3(960), 256, 0, stream>>>(Wq, Wk, Wv, Ww, Wqt, Wkt, Wvt, Wwt);
    fused_kernel<<<dim3(BW_), 512, LDS_BYTES, stream>>>(
        query, key_, value, Wqt, Wkt, Wvt, bq, bk, mask, Wwt, bw, out);
}